// Round 8
// baseline (131.184 us; speedup 1.0000x reference)
//
#include <hip/hip_runtime.h>

#pragma clang fp contract(off)

typedef unsigned long long u64;
typedef unsigned int u32;
typedef float f32x4 __attribute__((ext_vector_type(4)));

#define NB 8192
#define NW 128            // NB/64 bitmap words
#define NTILE 128         // 64-box tiles
#define NEDGEB 8192       // edge blocks
#define NLOGB 2048        // logit blocks
#define NMATB 4096        // mat blocks (32 jt-groups x 128 it)
#define CAPB 128          // per-mat-block edge capacity
#define ELDS 12288        // edges cached in LDS by k_scan5

// workspace layout (bytes)
#define OFF_EDGEQ 0                           // float[NB]
#define OFF_MP    (OFF_EDGEQ + NB * 4)        // float[NB]
#define OFF_KEEP  (OFF_MP    + NB * 4)        // u64[NW]
#define OFF_MAXPT (OFF_KEEP  + NW * 8)        // float[NTILE]
#define OFF_MAXA  (OFF_MAXPT + NTILE * 4)     // float[1] (+pad)
#define OFF_CNTB  (OFF_MAXA  + 256)           // u32[NMATB]
#define OFF_EDGEB (OFF_CNTB  + NMATB * 4)     // u32[NMATB*CAPB] (2 MB)

__device__ __forceinline__ float4 ldnt4(const float4* p) {
    f32x4 v = __builtin_nontemporal_load((const f32x4*)p);
    return make_float4(v.x, v.y, v.z, v.w);
}

__device__ __forceinline__ float haar3(float a, float b, float c, float d) {
    return fabsf(a + b - c - d) + fabsf(a - b + c - d) + fabsf(a - b - c + d);
}

// ---------- K1: fused front: edge | logit | mat (no cross-block ordering) ----------
__global__ __launch_bounds__(256) void k_front(const float* __restrict__ feat,
        const float* __restrict__ boxes, const float* __restrict__ scores,
        const float* __restrict__ logits, float* __restrict__ edgeq,
        float* __restrict__ mp, float* __restrict__ maxPT,
        u32* __restrict__ cntB, u32* __restrict__ edgesB) {
    __shared__ float sh[4][6][64];
    __shared__ u32 lcnt;
    __shared__ u32 lbuf[CAPB];
    __shared__ float wsum[4];
    int bid = blockIdx.x;
    int t = threadIdx.x;
    int wv = t >> 6, lane = t & 63;

    if (bid < NEDGEB) {
        // ---- edge quality ----
        int n = bid;
        const float* f = feat + (size_t)n * 4096;
        int hr = t >> 3, g = t & 7;
        const float4* row0 = (const float4*)(f + (2 * hr) * 64);
        const float4* row1 = (const float4*)(f + (2 * hr) * 64 + 64);
        float4 e0 = ldnt4(row0 + g);
        float4 e1 = ldnt4(row0 + 8 + g);
        float4 o0 = ldnt4(row1 + g);
        float4 o1 = ldnt4(row1 + 8 + g);
        float s = haar3(e0.x, e0.y, o0.x, o0.y) + haar3(e0.z, e0.w, o0.z, o0.w)
                + haar3(e1.x, e1.y, o1.x, o1.y) + haar3(e1.z, e1.w, o1.z, o1.w);
        for (int off = 32; off; off >>= 1) s += __shfl_down(s, off, 64);
        if (lane == 0) wsum[wv] = s;
        __syncthreads();
        if (t == 0) edgeq[n] = (wsum[0] + wsum[1] + wsum[2] + wsum[3]) * (0.5f / 3072.0f);
    } else if (bid < NEDGEB + NLOGB) {
        // ---- logit softmax-max ----
        int row = (bid - NEDGEB) * 4 + wv;
        const float4* p = (const float4*)(logits + (size_t)row * 1000);
        float4 v0 = ldnt4(p + lane);
        float4 v1 = ldnt4(p + lane + 64);
        float4 v2 = ldnt4(p + lane + 128);
        bool has3 = (lane + 192) < 250;
        float4 v3 = ldnt4(p + (has3 ? (lane + 192) : lane));
        float m = fmaxf(fmaxf(fmaxf(v0.x, v0.y), fmaxf(v0.z, v0.w)),
                        fmaxf(fmaxf(v1.x, v1.y), fmaxf(v1.z, v1.w)));
        m = fmaxf(m, fmaxf(fmaxf(v2.x, v2.y), fmaxf(v2.z, v2.w)));
        if (has3) m = fmaxf(m, fmaxf(fmaxf(v3.x, v3.y), fmaxf(v3.z, v3.w)));
        for (int off = 32; off; off >>= 1) m = fmaxf(m, __shfl_xor(m, off, 64));
        float s = __expf(v0.x - m) + __expf(v0.y - m) + __expf(v0.z - m) + __expf(v0.w - m)
                + __expf(v1.x - m) + __expf(v1.y - m) + __expf(v1.z - m) + __expf(v1.w - m)
                + __expf(v2.x - m) + __expf(v2.y - m) + __expf(v2.z - m) + __expf(v2.w - m);
        if (has3) s += __expf(v3.x - m) + __expf(v3.y - m) + __expf(v3.z - m) + __expf(v3.w - m);
        for (int off = 32; off; off >>= 1) s += __shfl_xor(s, off, 64);
        if (lane == 0) mp[row] = 1.0f / s;
    } else {
        // ---- sparse IoU edge list (per-block slots, no global atomics) ----
        int lin = bid - (NEDGEB + NLOGB);
        int it = lin >> 5;
        int jt = (lin & 31) * 4 + wv;
        bool dead = ((lin & 31) * 4 + 3) < it;
        bool active = !dead && (jt >= it);
        if (t == 0) lcnt = 0;
        int j0 = jt * 64;
        if (active) {
            float4 bj = ((const float4*)boxes)[j0 + lane];
            sh[wv][0][lane] = bj.x; sh[wv][1][lane] = bj.y;
            sh[wv][2][lane] = bj.z; sh[wv][3][lane] = bj.w;
            sh[wv][4][lane] = (bj.z - bj.x) * (bj.w - bj.y);
            sh[wv][5][lane] = scores[j0 + lane];
        }
        __syncthreads();
        if (active) {
            int i = it * 64 + lane;
            float4 bi = ((const float4*)boxes)[i];
            float X1 = bi.x, Y1 = bi.y, X2 = bi.z, Y2 = bi.w;
            float AR = (bi.z - bi.x) * (bi.w - bi.y);
            float SI = scores[i];
            bool diag = (jt == it);
            if (diag) {                               // exactly one wave per tile row
                float am = AR;
                for (int off = 32; off; off >>= 1) am = fmaxf(am, __shfl_xor(am, off, 64));
                if (lane == 0) maxPT[it] = am;        // plain write, single writer
            }
            #pragma unroll 4
            for (int b = 0; b < 64; ++b) {
                if (diag && b <= lane) continue;
                float xx1 = fmaxf(sh[wv][0][b], X1);
                float yy1 = fmaxf(sh[wv][1][b], Y1);
                float xx2 = fminf(sh[wv][2][b], X2);
                float yy2 = fminf(sh[wv][3][b], Y2);
                float iw = fmaxf(xx2 - xx1, 0.0f);
                float ih = fmaxf(yy2 - yy1, 0.0f);
                float inter = iw * ih;
                float denom = (AR + sh[wv][4][b]) - inter;
                // prefilter: iou>0.5 implies inter > 0.25*denom (huge margin)
                if (inter > 0.25f * denom) {
                    float iou = inter / denom;        // exact IEEE semantics
                    if (iou > 0.5f) {
                        int j = j0 + b;
                        float SJ = sh[wv][5][b];
                        bool ihi = (SI > SJ) || (SI == SJ && i < j);
                        u32 hi = ihi ? (u32)i : (u32)j;
                        u32 lo = ihi ? (u32)j : (u32)i;
                        u32 pos = atomicAdd(&lcnt, 1u);
                        if (pos < CAPB) lbuf[pos] = (hi << 16) | lo;
                    }
                }
            }
        }
        __syncthreads();
        u32 c = min(lcnt, (u32)CAPB);
        if (t == 0) cntB[lin] = c;                    // plain write, every block
        for (u32 e = t; e < c; e += 256) edgesB[(size_t)lin * CAPB + e] = lbuf[e];
    }
}

// ---------- K2: compact edges + maxA reduce + greedy NMS fixed point ----------
__global__ __launch_bounds__(256) void k_scan5(const u32* __restrict__ cntB,
        const u32* __restrict__ edgesB, const float* __restrict__ maxPT,
        float* __restrict__ maxab, u64* __restrict__ keepm) {
    __shared__ u64 dec[NW], kept[NW], keptIn[NW], pendIn[NW];
    __shared__ u32 eL[ELDS];
    __shared__ u32 gcnt;
    __shared__ int undec;
    int tid = threadIdx.x;
    if (tid < 64) {                                   // global max-area
        float v = fmaxf(maxPT[tid], maxPT[tid + 64]);
        for (int off = 32; off; off >>= 1) v = fmaxf(v, __shfl_xor(v, off, 64));
        if (tid == 0) *maxab = v;
    }
    if (tid < NW) { dec[tid] = 0; kept[tid] = 0; }
    if (tid == 0) gcnt = 0;
    __syncthreads();
    for (int b = tid; b < NMATB; b += 256) {          // gather per-block edge lists
        u32 c = cntB[b];
        if (c) {
            u32 base = atomicAdd(&gcnt, c);
            for (u32 e = 0; e < c; ++e)
                if (base + e < ELDS) eL[base + e] = edgesB[(size_t)b * CAPB + e];
        }
    }
    __syncthreads();
    int E = (int)min(gcnt, (u32)ELDS);
    for (int round = 0; round < NB; ++round) {
        if (tid < NW) { keptIn[tid] = 0; pendIn[tid] = 0; }
        if (tid == 0) undec = 0;
        __syncthreads();
        for (int e = tid; e < E; e += 256) {
            u32 pk = eL[e];
            int hi = (int)(pk >> 16), lo = (int)(pk & 0xFFFFu);
            bool d = (dec[hi >> 6] >> (hi & 63)) & 1ull;
            bool k = (kept[hi >> 6] >> (hi & 63)) & 1ull;
            if (!d)     atomicOr(&pendIn[lo >> 6], 1ull << (lo & 63));
            else if (k) atomicOr(&keptIn[lo >> 6], 1ull << (lo & 63));
        }
        __syncthreads();
        if (tid < NW) {
            u64 und = ~dec[tid];
            u64 sup = und & keptIn[tid];
            u64 kp  = und & ~keptIn[tid] & ~pendIn[tid];
            kept[tid] |= kp;
            dec[tid]  |= sup | kp;
            if (und & ~(sup | kp)) undec = 1;
        }
        __syncthreads();
        if (!undec) break;
    }
    if (tid < NW) keepm[tid] = kept[tid];
}

// ---------- K3: final outputs, quality computed inline ----------
__global__ __launch_bounds__(256) void k_out(const float* __restrict__ boxes,
        const float* __restrict__ scores, const float* __restrict__ edgeq,
        const float* __restrict__ mp, const float* __restrict__ maxab,
        const u64* __restrict__ keepmask, const int* __restrict__ labels,
        float* __restrict__ out) {
    int n = blockIdx.x * 256 + threadIdx.x;
    bool kept = (keepmask[n >> 6] >> (n & 63)) & 1ull;
    float kf = kept ? 1.0f : 0.0f;
    float4 b = ((const float4*)boxes)[n];
    float w = b.z - b.x, h = b.w - b.y;
    float area = w * h;
    float aspect = fminf(w / h, h / w);
    float maxA = *maxab;
    float ascore = area / (maxA + 1e-6f);
    ascore = fminf(fmaxf(ascore, 0.f), 1.f);
    float sc = scores[n];
    float det = sc * mp[n] * (aspect * ascore);
    float q = det * 0.4f + 0.3f + edgeq[n] * 0.3f;
    float* o = out + (size_t)n * 6;
    o[0] = b.x * kf; o[1] = b.y * kf; o[2] = b.z * kf; o[3] = b.w * kf;
    o[4] = sc * kf;
    o[5] = q * kf;
    out[6 * NB + n] = kf;
    out[7 * NB + n] = (float)labels[n];
}

extern "C" void kernel_launch(void* const* d_in, const int* in_sizes, int n_in,
                              void* d_out, int out_size, void* d_ws, size_t ws_size,
                              hipStream_t stream) {
    const float* boxes  = (const float*)d_in[0];
    const float* scores = (const float*)d_in[1];
    const float* logits = (const float*)d_in[2];
    const float* feats  = (const float*)d_in[3];
    const int*   labels = (const int*)d_in[4];
    float* out = (float*)d_out;
    char* ws = (char*)d_ws;

    float* edgeq  = (float*)(ws + OFF_EDGEQ);
    float* mp     = (float*)(ws + OFF_MP);
    u64*   keepm  = (u64*)(ws + OFF_KEEP);
    float* maxPT  = (float*)(ws + OFF_MAXPT);
    float* maxab  = (float*)(ws + OFF_MAXA);
    u32*   cntB   = (u32*)(ws + OFF_CNTB);
    u32*   edgesB = (u32*)(ws + OFF_EDGEB);

    k_front<<<NEDGEB + NLOGB + NMATB, 256, 0, stream>>>(feats, boxes, scores, logits,
                                                        edgeq, mp, maxPT, cntB, edgesB);
    k_scan5<<<1, 256, 0, stream>>>(cntB, edgesB, maxPT, maxab, keepm);
    k_out<<<NB / 256, 256, 0, stream>>>(boxes, scores, edgeq, mp, maxab, keepm, labels, out);
}

// Round 9
// 114.231 us; speedup vs baseline: 1.1484x; 1.1484x over previous
//
#include <hip/hip_runtime.h>

#pragma clang fp contract(off)

typedef unsigned long long u64;
typedef unsigned int u32;
typedef float f32x4 __attribute__((ext_vector_type(4)));

#define NB 8192
#define NW 128          // NB/64 bitmap words
#define EMAX 16384      // edge-list capacity (expect ~2-3k)
#define ELDS 12288      // edges cached in LDS by k_scan4
#define NEDGEB 8192     // feature blocks in k_front
#define NLOGB 2048      // logit blocks in k_front

// workspace layout (bytes)
#define OFF_EDGEQ 0                          // float[NB]
#define OFF_MP    (OFF_EDGEQ + NB * 4)       // float[NB]
#define OFF_KEEP  (OFF_MP    + NB * 4)       // u64[NW]
#define OFF_ECNT  (OFF_KEEP  + NW * 8)       // u32[1]
#define OFF_MAXA  (OFF_ECNT  + 64)           // u32[1] (float bits)
#define OFF_EDGES (OFF_MAXA  + 192)          // u32[EMAX]

__device__ __forceinline__ float4 ldnt4(const float4* p) {
    f32x4 v = __builtin_nontemporal_load((const f32x4*)p);
    return make_float4(v.x, v.y, v.z, v.w);
}

__device__ __forceinline__ float haar3(float a, float b, float c, float d) {
    return fabsf(a + b - c - d) + fabsf(a - b + c - d) + fabsf(a - b - c + d);
}

// ---------- K1: fused streaming front: edge quality | logit softmax-max ----------
// Both paths are pure streaming with ~16B LDS and similar register profiles.
__global__ __launch_bounds__(256) void k_front(const float* __restrict__ feat,
        const float* __restrict__ logits, float* __restrict__ edgeq,
        float* __restrict__ mp, u32* __restrict__ ecnt, u32* __restrict__ maxab) {
    int bid = blockIdx.x;
    int t = threadIdx.x;
    int wv = t >> 6, lane = t & 63;
    if (bid < NEDGEB) {
        // ---- edge quality (one box per block) ----
        if (bid == 0 && t == 0) { *ecnt = 0; *maxab = 0; }
        const float* f = feat + (size_t)bid * 4096;
        int hr = t >> 3, g = t & 7;
        const float4* row0 = (const float4*)(f + (2 * hr) * 64);
        const float4* row1 = (const float4*)(f + (2 * hr) * 64 + 64);
        float4 e0 = ldnt4(row0 + g);
        float4 e1 = ldnt4(row0 + 8 + g);
        float4 o0 = ldnt4(row1 + g);
        float4 o1 = ldnt4(row1 + 8 + g);
        float s = haar3(e0.x, e0.y, o0.x, o0.y) + haar3(e0.z, e0.w, o0.z, o0.w)
                + haar3(e1.x, e1.y, o1.x, o1.y) + haar3(e1.z, e1.w, o1.z, o1.w);
        for (int off = 32; off; off >>= 1) s += __shfl_down(s, off, 64);
        __shared__ float wsum[4];
        if (lane == 0) wsum[wv] = s;
        __syncthreads();
        if (t == 0) edgeq[bid] = (wsum[0] + wsum[1] + wsum[2] + wsum[3]) * (0.5f / 3072.0f);
    } else {
        // ---- logit softmax-max (4 rows per block, 1 wave per row) ----
        int row = (bid - NEDGEB) * 4 + wv;
        const float4* p = (const float4*)(logits + (size_t)row * 1000);
        float4 v0 = ldnt4(p + lane);
        float4 v1 = ldnt4(p + lane + 64);
        float4 v2 = ldnt4(p + lane + 128);
        bool has3 = (lane + 192) < 250;
        float4 v3 = ldnt4(p + (has3 ? (lane + 192) : lane));
        float m = fmaxf(fmaxf(fmaxf(v0.x, v0.y), fmaxf(v0.z, v0.w)),
                        fmaxf(fmaxf(v1.x, v1.y), fmaxf(v1.z, v1.w)));
        m = fmaxf(m, fmaxf(fmaxf(v2.x, v2.y), fmaxf(v2.z, v2.w)));
        if (has3) m = fmaxf(m, fmaxf(fmaxf(v3.x, v3.y), fmaxf(v3.z, v3.w)));
        for (int off = 32; off; off >>= 1) m = fmaxf(m, __shfl_xor(m, off, 64));
        float s = __expf(v0.x - m) + __expf(v0.y - m) + __expf(v0.z - m) + __expf(v0.w - m)
                + __expf(v1.x - m) + __expf(v1.y - m) + __expf(v1.z - m) + __expf(v1.w - m)
                + __expf(v2.x - m) + __expf(v2.y - m) + __expf(v2.z - m) + __expf(v2.w - m);
        if (has3) s += __expf(v3.x - m) + __expf(v3.y - m) + __expf(v3.z - m) + __expf(v3.w - m);
        for (int off = 32; off; off >>= 1) s += __shfl_xor(s, off, 64);
        if (lane == 0) mp[row] = 1.0f / s;
    }
}

// ---------- K2: sparse IoU edge list + global max-area (diag waves) ----------
__global__ __launch_bounds__(256) void k_mat(const float* __restrict__ boxes,
        const float* __restrict__ scores, u32* __restrict__ ecnt,
        u32* __restrict__ edges, u32* __restrict__ maxab) {
    int it = blockIdx.y;
    if ((int)blockIdx.x * 4 + 3 < it) return;        // uniform: whole block dead
    int wv = threadIdx.x >> 6, lane = threadIdx.x & 63;
    int jt = blockIdx.x * 4 + wv;
    bool active = (jt >= it);
    __shared__ float sh[4][6][64];
    if (active) {
        int j0 = jt * 64;
        float4 bj = ((const float4*)boxes)[j0 + lane];
        sh[wv][0][lane] = bj.x; sh[wv][1][lane] = bj.y;
        sh[wv][2][lane] = bj.z; sh[wv][3][lane] = bj.w;
        sh[wv][4][lane] = (bj.z - bj.x) * (bj.w - bj.y);
        sh[wv][5][lane] = scores[j0 + lane];
    }
    __syncthreads();
    if (!active) return;
    int j0 = jt * 64;
    int i = it * 64 + lane;
    float4 bi = ((const float4*)boxes)[i];
    float X1 = bi.x, Y1 = bi.y, X2 = bi.z, Y2 = bi.w;
    float AR = (bi.z - bi.x) * (bi.w - bi.y);
    float SI = scores[i];
    bool diag = (jt == it);
    if (diag) {                                      // exactly one wave per tile
        float am = AR;
        for (int off = 32; off; off >>= 1) am = fmaxf(am, __shfl_xor(am, off, 64));
        if (lane == 0) atomicMax(maxab, __float_as_uint(am));  // positive floats: bit-monotone
    }
    #pragma unroll 4
    for (int b = 0; b < 64; ++b) {
        if (diag && b <= lane) continue;
        float xx1 = fmaxf(sh[wv][0][b], X1);
        float yy1 = fmaxf(sh[wv][1][b], Y1);
        float xx2 = fminf(sh[wv][2][b], X2);
        float yy2 = fminf(sh[wv][3][b], Y2);
        float iw = fmaxf(xx2 - xx1, 0.0f);
        float ih = fmaxf(yy2 - yy1, 0.0f);
        float inter = iw * ih;
        float denom = (AR + sh[wv][4][b]) - inter;
        // prefilter: iou>0.5 implies inter > 0.25*denom (huge margin)
        if (inter > 0.25f * denom) {
            float iou = inter / denom;            // exact IEEE semantics
            if (iou > 0.5f) {
                int j = j0 + b;
                float SJ = sh[wv][5][b];
                // priority: higher score wins; tie -> smaller original index
                bool ihi = (SI > SJ) || (SI == SJ && i < j);
                u32 hi = ihi ? (u32)i : (u32)j;
                u32 lo = ihi ? (u32)j : (u32)i;
                u32 pos = atomicAdd(ecnt, 1u);
                if (pos < EMAX) edges[pos] = (hi << 16) | lo;
            }
        }
    }
}

// ---------- K3: round-based greedy NMS fixed point (edges cached in LDS) ----------
__global__ __launch_bounds__(256) void k_scan4(const u32* __restrict__ ecnt,
        const u32* __restrict__ edges, u64* __restrict__ keepm) {
    __shared__ u64 dec[NW], kept[NW], keptIn[NW], pendIn[NW];
    __shared__ u32 eL[ELDS];
    __shared__ int undec;
    int tid = threadIdx.x;
    int E = (int)min(*ecnt, (u32)EMAX);
    if (tid < NW) { dec[tid] = 0; kept[tid] = 0; }
    for (int e = tid; e < E && e < ELDS; e += 256) eL[e] = edges[e];
    __syncthreads();
    for (int round = 0; round < NB; ++round) {
        if (tid < NW) { keptIn[tid] = 0; pendIn[tid] = 0; }
        if (tid == 0) undec = 0;
        __syncthreads();
        for (int e = tid; e < E; e += 256) {
            u32 pk = (e < ELDS) ? eL[e] : edges[e];
            int hi = (int)(pk >> 16), lo = (int)(pk & 0xFFFFu);
            bool d = (dec[hi >> 6] >> (hi & 63)) & 1ull;
            bool k = (kept[hi >> 6] >> (hi & 63)) & 1ull;
            if (!d)     atomicOr(&pendIn[lo >> 6], 1ull << (lo & 63));
            else if (k) atomicOr(&keptIn[lo >> 6], 1ull << (lo & 63));
        }
        __syncthreads();
        if (tid < NW) {
            u64 und = ~dec[tid];
            u64 sup = und & keptIn[tid];
            u64 kp  = und & ~keptIn[tid] & ~pendIn[tid];
            kept[tid] |= kp;
            dec[tid]  |= sup | kp;
            if (und & ~(sup | kp)) undec = 1;
        }
        __syncthreads();
        if (!undec) break;
    }
    if (tid < NW) keepm[tid] = kept[tid];
}

// ---------- K4: final outputs, quality computed inline ----------
__global__ __launch_bounds__(256) void k_out(const float* __restrict__ boxes,
        const float* __restrict__ scores, const float* __restrict__ edgeq,
        const float* __restrict__ mp, const u32* __restrict__ maxab,
        const u64* __restrict__ keepmask, const int* __restrict__ labels,
        float* __restrict__ out) {
    int n = blockIdx.x * 256 + threadIdx.x;
    bool kept = (keepmask[n >> 6] >> (n & 63)) & 1ull;
    float kf = kept ? 1.0f : 0.0f;
    float4 b = ((const float4*)boxes)[n];
    float w = b.z - b.x, h = b.w - b.y;
    float area = w * h;
    float aspect = fminf(w / h, h / w);
    float maxA = __uint_as_float(*maxab);
    float ascore = area / (maxA + 1e-6f);
    ascore = fminf(fmaxf(ascore, 0.f), 1.f);
    float sc = scores[n];
    float det = sc * mp[n] * (aspect * ascore);
    float q = det * 0.4f + 0.3f + edgeq[n] * 0.3f;
    float* o = out + (size_t)n * 6;
    o[0] = b.x * kf; o[1] = b.y * kf; o[2] = b.z * kf; o[3] = b.w * kf;
    o[4] = sc * kf;
    o[5] = q * kf;
    out[6 * NB + n] = kf;
    out[7 * NB + n] = (float)labels[n];
}

extern "C" void kernel_launch(void* const* d_in, const int* in_sizes, int n_in,
                              void* d_out, int out_size, void* d_ws, size_t ws_size,
                              hipStream_t stream) {
    const float* boxes  = (const float*)d_in[0];
    const float* scores = (const float*)d_in[1];
    const float* logits = (const float*)d_in[2];
    const float* feats  = (const float*)d_in[3];
    const int*   labels = (const int*)d_in[4];
    float* out = (float*)d_out;
    char* ws = (char*)d_ws;

    float* edgeq  = (float*)(ws + OFF_EDGEQ);
    float* mp     = (float*)(ws + OFF_MP);
    u64*   keepm  = (u64*)(ws + OFF_KEEP);
    u32*   ecnt   = (u32*)(ws + OFF_ECNT);
    u32*   maxab  = (u32*)(ws + OFF_MAXA);
    u32*   edges  = (u32*)(ws + OFF_EDGES);

    k_front<<<NEDGEB + NLOGB, 256, 0, stream>>>(feats, logits, edgeq, mp, ecnt, maxab);
    dim3 gmat(32, NW);
    k_mat<<<gmat, 256, 0, stream>>>(boxes, scores, ecnt, edges, maxab);
    k_scan4<<<1, 256, 0, stream>>>(ecnt, edges, keepm);
    k_out<<<NB / 256, 256, 0, stream>>>(boxes, scores, edgeq, mp, maxab, keepm, labels, out);
}